// Round 1
// baseline (1272.618 us; speedup 1.0000x reference)
//
#include <hip/hip_runtime.h>
#include <stdint.h>

#define AS1 __attribute__((address_space(1)))
#define AS3 __attribute__((address_space(3)))

typedef __bf16 bf16x8 __attribute__((ext_vector_type(8)));
typedef float  f32x4  __attribute__((ext_vector_type(4)));

__device__ __forceinline__ void gl_lds16(const void* g, void* l) {
    __builtin_amdgcn_global_load_lds((AS1 void*)g, (AS3 void*)l, 16, 0, 0);
}

// f32 -> bf16 with round-to-nearest-even (manual, no NaN inputs here)
__device__ __forceinline__ ushort f2bf(float f) {
    unsigned x = __float_as_uint(f);
    return (ushort)((x + 0x7fffu + ((x >> 16) & 1u)) >> 16);
}

// ---------------------------------------------------------------------------
// GEMM: C[m][n] = sum_k A[m][k] * BT[n][k]   (128x128 tile, BK=32, bf16 MFMA)
// AMODE 0: A flat [m][K] (A,B offset by blockIdx.z * M*K / N*K)
// AMODE 1: A = padded-NHWC conv gather: m=(b*49+p), k=(s*Cin+ci),
//          A[m][k] = xpad[b][p/7 + s/3][p%7 + s%3][ci]   (9x9 padded spatial)
// EPI 0: conv_reduce -> OF = x f32 [b][512][49]; OU0 = xpad bf16 [b][9][9][512]
// EPI 1: conv_kv     -> n<512: OU0 = kbuf [p][j][512]; else OU1 = vbuf [p][j][512]
// EPI 2: scores      -> OF[z*256+m][n]  (256 wide)
// EPI 3: PV          -> OF[z*256+m][n]  (512 wide)
// EPI 4: conv_out    -> OF[(b*512+n)*49+p] = AUX[idx] + val
// ---------------------------------------------------------------------------
template <int AMODE, int EPI>
__global__ __launch_bounds__(256, 3) void gemm_bt(
    const ushort* __restrict__ A, const ushort* __restrict__ BT,
    float* __restrict__ OF, ushort* __restrict__ OU0, ushort* __restrict__ OU1,
    const float* __restrict__ AUX, int M, int N, int K, int Cin, int Ksegs) {
    __shared__ ushort As[128 * 32];
    __shared__ ushort Bs[128 * 32];

    const int t = threadIdx.x;
    const int lane = t & 63;
    const int wave = t >> 6;
    const int wm = wave & 1, wn = wave >> 1;
    const int blockN = blockIdx.x * 128;
    const int blockM = blockIdx.y * 128;
    const int z = blockIdx.z;

    const char* Ab = (const char*)A;
    const char* Bb = (const char*)BT;
    if (AMODE == 0) {
        Ab += (size_t)z * (size_t)M * (size_t)K * 2;
        Bb += (size_t)z * (size_t)N * (size_t)K * 2;
    }

    const int rS = t >> 2;              // staging row 0..63 (and +64)
    const int seg = (t & 3) * 16;       // 16B segment within a 64B K-tile row

    unsigned abase0, abase1;
    if (AMODE == 1) {
        int m0 = blockM + rS, m1 = m0 + 64;
        int b0 = m0 / 49, p0 = m0 % 49;
        int b1 = m1 / 49, p1 = m1 % 49;
        abase0 = (unsigned)(((b0 * 9 + p0 / 7) * 9 + p0 % 7) * Cin);
        abase1 = (unsigned)(((b1 * 9 + p1 / 7) * 9 + p1 % 7) * Cin);
    } else {
        abase0 = (unsigned)((blockM + rS) * K);
        abase1 = abase0 + (unsigned)(64 * K);
    }
    const unsigned bbase0 = (unsigned)((blockN + rS) * K);
    const unsigned bbase1 = bbase0 + (unsigned)(64 * K);

    f32x4 zero = {0.f, 0.f, 0.f, 0.f};
    f32x4 acc[4][4];
    for (int i = 0; i < 4; i++)
        for (int j = 0; j < 4; j++) acc[i][j] = zero;

    const int citers = (AMODE == 1) ? (Cin / 32) : (K / 32);
    const int nseg = (AMODE == 1) ? Ksegs : 1;

    unsigned kbyteB = 0;
    for (int s = 0; s < nseg; ++s) {
        const char *aseg0, *aseg1;
        if (AMODE == 1) {
            unsigned shift = (unsigned)(((s / 3) * 9 + (s % 3)) * Cin);
            aseg0 = Ab + (size_t)(abase0 + shift) * 2 + seg;
            aseg1 = Ab + (size_t)(abase1 + shift) * 2 + seg;
        } else {
            aseg0 = Ab + (size_t)abase0 * 2 + seg;
            aseg1 = Ab + (size_t)abase1 * 2 + seg;
        }
        const char* bseg0 = Bb + (size_t)bbase0 * 2 + seg + kbyteB;
        const char* bseg1 = Bb + (size_t)bbase1 * 2 + seg + kbyteB;

        for (int ct = 0; ct < citers; ++ct) {
            __syncthreads();  // previous compute done reading LDS
            gl_lds16(aseg0 + ct * 64, (char*)As + t * 16);
            gl_lds16(aseg1 + ct * 64, (char*)As + 4096 + t * 16);
            gl_lds16(bseg0 + ct * 64, (char*)Bs + t * 16);
            gl_lds16(bseg1 + ct * 64, (char*)Bs + 4096 + t * 16);
            __syncthreads();  // staging visible (compiler drains vmcnt before barrier)

            const ushort* Ap = As + (wm * 64 + (lane & 15)) * 32 + (lane >> 4) * 8;
            const ushort* Bp = Bs + (wn * 64 + (lane & 15)) * 32 + (lane >> 4) * 8;
            bf16x8 af[4], bfr[4];
#pragma unroll
            for (int i = 0; i < 4; i++) {
                af[i] = *(const bf16x8*)(Ap + i * 16 * 32);
                bfr[i] = *(const bf16x8*)(Bp + i * 16 * 32);
            }
#pragma unroll
            for (int i = 0; i < 4; i++)
#pragma unroll
                for (int j = 0; j < 4; j++)
                    acc[i][j] = __builtin_amdgcn_mfma_f32_16x16x32_bf16(af[i], bfr[j], acc[i][j], 0, 0, 0);
        }
        kbyteB += (unsigned)citers * 64;
    }

    // epilogue: C/D layout col=lane&15, row=(lane>>4)*4+r  [m89/m91 verified]
    const int mrow = (lane >> 4) * 4;
    const int ncol = lane & 15;
#pragma unroll
    for (int i = 0; i < 4; i++) {
#pragma unroll
        for (int j = 0; j < 4; j++) {
            f32x4 v = acc[i][j];
#pragma unroll
            for (int r = 0; r < 4; r++) {
                int m = blockM + wm * 64 + i * 16 + mrow + r;
                int n = blockN + wn * 64 + j * 16 + ncol;
                float val = v[r];
                if (EPI == 0) {
                    int b = m / 49, p = m % 49;
                    OF[(size_t)(b * 512 + n) * 49 + p] = val;
                    OU0[(size_t)((b * 9 + p / 7 + 1) * 9 + p % 7 + 1) * 512 + n] = f2bf(val);
                } else if (EPI == 1) {
                    int j2 = m / 49, p = m % 49;
                    if (n < 512)
                        OU0[(size_t)(p * 256 + j2) * 512 + n] = f2bf(val);
                    else
                        OU1[(size_t)(p * 256 + j2) * 512 + (n - 512)] = f2bf(val);
                } else if (EPI == 2) {
                    OF[((size_t)z * 256 + m) * 256 + n] = val;
                } else if (EPI == 3) {
                    OF[((size_t)z * 256 + m) * 512 + n] = val;
                } else {
                    int b = m / 49, p = m % 49;
                    size_t idx = (size_t)(b * 512 + n) * 49 + p;
                    OF[idx] = AUX[idx] + val;
                }
            }
        }
    }
}

// zero a range (uint4 grid-stride)
__global__ void zero_k(uint4* __restrict__ p, int n4) {
    uint4 zz = {0, 0, 0, 0};
    for (int i = blockIdx.x * blockDim.x + threadIdx.x; i < n4; i += gridDim.x * blockDim.x) p[i] = zz;
}

// bbox_featx f32 [b][2304][49] -> x0T bf16 [b][9][9][2304] (interior only)
__global__ void cast_x0_k(const float* __restrict__ in, ushort* __restrict__ out) {
    int id = blockIdx.x * 256 + threadIdx.x;  // 256*49*1152
    int ci = (id % 1152) * 2;
    int rest = id / 1152;
    int p = rest % 49;
    int b = rest / 49;
    float v0 = in[(size_t)(b * 2304 + ci) * 49 + p];
    float v1 = in[(size_t)(b * 2304 + ci + 1) * 49 + p];
    unsigned u = (unsigned)f2bf(v0) | ((unsigned)f2bf(v1) << 16);
    *(unsigned*)(out + (size_t)((b * 9 + p / 7 + 1) * 9 + p % 7 + 1) * 2304 + ci) = u;
}

// weight f32 [co][Cin][9] -> bf16 [co][9][Cin]  (one block per co)
__global__ void cast_w_k(const float* __restrict__ in, ushort* __restrict__ out, int Cin) {
    __shared__ float lds[256 * 9];
    int co = blockIdx.x, t = threadIdx.x;
    for (int ci0 = 0; ci0 < Cin; ci0 += 256) {
        const float* src = in + ((size_t)co * Cin + ci0 + t) * 9;
#pragma unroll
        for (int j = 0; j < 9; j++) lds[t * 9 + j] = src[j];
        __syncthreads();
#pragma unroll
        for (int s = 0; s < 9; s++) out[((size_t)co * 9 + s) * Cin + ci0 + t] = f2bf(lds[t * 9 + s]);
        __syncthreads();
    }
}

// windowed sums of w_q per spatial pos: WSQ[p][ci][co]
__global__ void wsq_k(const float* __restrict__ wq, float* __restrict__ WSQ) {
    int p = blockIdx.x, co = threadIdx.x;
    int h = p / 7, w = p % 7;
#pragma unroll
    for (int ci = 0; ci < 2; ci++) {
        float a = 0.f;
        for (int kh = 0; kh < 3; kh++) {
            int hi = h + kh - 1;
            if (hi < 0 || hi > 6) continue;
            for (int kw = 0; kw < 3; kw++) {
                int wi = w + kw - 1;
                if (wi < 0 || wi > 6) continue;
                a += wq[(((size_t)co * 2 + ci) * 3 + kh) * 3 + kw];
            }
        }
        WSQ[((size_t)p * 2 + ci) * 512 + co] = a;
    }
}

// q bf16 [p][b][512], scaled by 1/sqrt(512)
__global__ void qgen_k(const float* __restrict__ status, const float* __restrict__ rois,
                       const float* __restrict__ WSQ, ushort* __restrict__ qb) {
    int b = blockIdx.x, p = blockIdx.y, t = threadIdx.x;
    float st0 = status[b * 2], st1 = rois[b * 2 + 1];
    int c = t * 2;
    const float* w0 = WSQ + (size_t)p * 2 * 512;
    const float sc = 0.04419417382415922f;  // 1/sqrt(512)
    float q0 = (st0 * w0[c] + st1 * w0[512 + c]) * sc;
    float q1 = (st0 * w0[c + 1] + st1 * w0[512 + c + 1]) * sc;
    unsigned u = (unsigned)f2bf(q0) | ((unsigned)f2bf(q1) << 16);
    *(unsigned*)(qb + ((size_t)p * 256 + b) * 512 + c) = u;
}

// softmax over rows of 256 (S f32 -> att bf16), one wave per row
__global__ void softmax_k(const float* __restrict__ S, ushort* __restrict__ att) {
    int row = blockIdx.x * 4 + (threadIdx.x >> 6);
    int lane = threadIdx.x & 63;
    const float4 sv = *(const float4*)(S + (size_t)row * 256 + lane * 4);
    float m = fmaxf(fmaxf(sv.x, sv.y), fmaxf(sv.z, sv.w));
    for (int o = 32; o > 0; o >>= 1) m = fmaxf(m, __shfl_xor(m, o));
    float e0 = __expf(sv.x - m), e1 = __expf(sv.y - m);
    float e2 = __expf(sv.z - m), e3 = __expf(sv.w - m);
    float s = e0 + e1 + e2 + e3;
    for (int o = 32; o > 0; o >>= 1) s += __shfl_xor(s, o);
    float inv = 1.f / s;
    ushort4 o4;
    o4.x = f2bf(e0 * inv); o4.y = f2bf(e1 * inv);
    o4.z = f2bf(e2 * inv); o4.w = f2bf(e3 * inv);
    *(ushort4*)(att + (size_t)row * 256 + lane * 4) = o4;
}

// vbuf [p][j][512] -> vbufT [p][512][j] (64x64 LDS tiles)
__global__ void transpose_v_k(const ushort* __restrict__ vb, ushort* __restrict__ vt) {
    __shared__ ushort tl[64][66];
    int p = blockIdx.z, j0 = blockIdx.y * 64, c0 = blockIdx.x * 64;
    int t = threadIdx.x;
#pragma unroll
    for (int i = 0; i < 4; i++) {
        int e = i * 1024 + t * 4;
        int j = e >> 6, c = e & 63;
        ushort4 v = *(const ushort4*)(vb + ((size_t)p * 256 + j0 + j) * 512 + c0 + c);
        tl[j][c] = v.x; tl[j][c + 1] = v.y; tl[j][c + 2] = v.z; tl[j][c + 3] = v.w;
    }
    __syncthreads();
#pragma unroll
    for (int i = 0; i < 4; i++) {
        int e = i * 1024 + t * 4;
        int cc = e >> 6, jj = e & 63;
        ushort4 o;
        o.x = tl[jj][cc]; o.y = tl[jj + 1][cc]; o.z = tl[jj + 2][cc]; o.w = tl[jj + 3][cc];
        *(ushort4*)(vt + ((size_t)p * 512 + c0 + cc) * 256 + j0 + jj) = o;
    }
}

// layernorm over (c,p) per b + gamma/beta + relu -> vpad bf16 [b][9][9][512] (borders zeroed here)
__global__ __launch_bounds__(256) void ln_k(const float* __restrict__ virt, const float* __restrict__ gamma,
                                            const float* __restrict__ beta, ushort* __restrict__ vp) {
    int b = blockIdx.x, t = threadIdx.x;
    float s1 = 0.f, s2 = 0.f;
    for (int p = 0; p < 49; p++) {
        const float* r = virt + ((size_t)p * 256 + b) * 512;
        float a = r[t], c = r[t + 256];
        s1 += a + c;
        s2 += a * a + c * c;
    }
    for (int o = 32; o > 0; o >>= 1) { s1 += __shfl_xor(s1, o); s2 += __shfl_xor(s2, o); }
    __shared__ float red[8];
    int wave = t >> 6, lane = t & 63;
    if (lane == 0) { red[wave] = s1; red[4 + wave] = s2; }
    __syncthreads();
    float S1 = red[0] + red[1] + red[2] + red[3];
    float S2 = red[4] + red[5] + red[6] + red[7];
    float mean = S1 * (1.f / 25088.f);
    float var = S2 * (1.f / 25088.f) - mean * mean;
    float rs = rsqrtf(var + 1e-5f);
    float g0 = gamma[t], b0 = beta[t], g1 = gamma[t + 256], b1 = beta[t + 256];
    for (int p = 0; p < 49; p++) {
        const float* r = virt + ((size_t)p * 256 + b) * 512;
        size_t ob = ((size_t)(b * 9 + p / 7 + 1) * 9 + p % 7 + 1) * 512;
        vp[ob + t] = f2bf(fmaxf((r[t] - mean) * rs * g0 + b0, 0.f));
        vp[ob + t + 256] = f2bf(fmaxf((r[t + 256] - mean) * rs * g1 + b1, 0.f));
    }
#pragma unroll
    for (int e = 0; e < 32; e++) {  // zero padding borders (18 + 14 positions)
        int hp, wp;
        if (e < 9) { hp = 0; wp = e; }
        else if (e < 18) { hp = 8; wp = e - 9; }
        else { int e2 = e - 18; hp = 1 + (e2 >> 1); wp = (e2 & 1) ? 8 : 0; }
        size_t ob = ((size_t)(b * 9 + hp) * 9 + wp) * 512;
        vp[ob + t] = 0;
        vp[ob + t + 256] = 0;
    }
}

extern "C" void kernel_launch(void* const* d_in, const int* in_sizes, int n_in,
                              void* d_out, int out_size, void* d_ws, size_t ws_size,
                              hipStream_t stream) {
    const float* status = (const float*)d_in[0];
    const float* rois = (const float*)d_in[1];
    const float* bfeat = (const float*)d_in[2];
    const float* w_red = (const float*)d_in[3];
    const float* w_q = (const float*)d_in[4];
    const float* w_k = (const float*)d_in[5];
    const float* w_v = (const float*)d_in[6];
    const float* w_o = (const float*)d_in[7];
    const float* gamma = (const float*)d_in[8];
    const float* beta = (const float*)d_in[9];
    float* out = (float*)d_out;
    char* ws = (char*)d_ws;

    // workspace layout (overlaid by lifetime), ~191 MB peak
    const size_t OFF_XT1 = 0;                       // 21,233,664  xpad-of-x (later vbufT)
    const size_t OFF_C = 21233664;                  // 95,551,488  x0T (later S/att/virt/q/vpad)
    const size_t OFF_S = OFF_C;                     // 12,845,056
    const size_t OFF_ATT = OFF_C + 12845056;        //  6,422,528
    const size_t OFF_VIRT = OFF_ATT + 6422528;      // 25,690,112
    const size_t OFF_QB = OFF_VIRT + 25690112;      // 12,845,056
    const size_t OFF_VPAD = OFF_QB + 12845056;      // 21,233,664 (ends 79.0MB < 95.5MB)
    const size_t OFF_W1T = OFF_C + 95551488;        // 21,233,664  w1T (later kbuf)
    const size_t OFF_WKVT = OFF_W1T + 21233664;     //  9,437,184
    const size_t OFF_WOT = OFF_WKVT + 9437184;      //  4,718,592
    const size_t OFF_XF = OFF_WOT + 4718592;        // 25,690,112  x f32
    const size_t OFF_VB = OFF_XF + 25690112;        // 12,845,056  vbuf
    const size_t OFF_WSQ = OFF_VB + 12845056;       //    200,704
    const size_t NEED = OFF_WSQ + 200704;           // 190,910,464
    if (ws_size < NEED) return;  // workspace too small: leave output poisoned (visible failure)

    // 1) zero x0T + xpad(x) regions (contiguous [0, OFF_W1T))
    zero_k<<<2048, 256, 0, stream>>>((uint4*)ws, (int)(OFF_W1T / 16));
    // 2) cast/layout inputs
    cast_x0_k<<<56448, 256, 0, stream>>>(bfeat, (ushort*)(ws + OFF_C));
    cast_w_k<<<512, 256, 0, stream>>>(w_red, (ushort*)(ws + OFF_W1T), 2304);
    cast_w_k<<<512, 256, 0, stream>>>(w_k, (ushort*)(ws + OFF_WKVT), 512);
    cast_w_k<<<512, 256, 0, stream>>>(w_v, (ushort*)(ws + OFF_WKVT) + (size_t)512 * 9 * 512, 512);
    cast_w_k<<<512, 256, 0, stream>>>(w_o, (ushort*)(ws + OFF_WOT), 512);
    // 3) conv_reduce: x = conv(bbox, w_reduce)  [M=12544,N=512,K=20736]
    gemm_bt<1, 0><<<dim3(4, 98, 1), 256, 0, stream>>>(
        (ushort*)(ws + OFF_C), (ushort*)(ws + OFF_W1T),
        (float*)(ws + OFF_XF), (ushort*)(ws + OFF_XT1), nullptr, nullptr,
        12544, 512, 20736, 2304, 9);
    // 4) k & v convs fused (N=1024, K=4608); kbuf overwrites w1T region
    gemm_bt<1, 1><<<dim3(8, 98, 1), 256, 0, stream>>>(
        (ushort*)(ws + OFF_XT1), (ushort*)(ws + OFF_WKVT),
        nullptr, (ushort*)(ws + OFF_W1T), (ushort*)(ws + OFF_VB), nullptr,
        12544, 1024, 4608, 512, 9);
    // 5) q path (conv of spatially-constant field -> windowed weight sums)
    wsq_k<<<49, 512, 0, stream>>>(w_q, (float*)(ws + OFF_WSQ));
    qgen_k<<<dim3(256, 49), 256, 0, stream>>>(status, rois, (float*)(ws + OFF_WSQ), (ushort*)(ws + OFF_QB));
    // 6) V^T for PV gemm (vbufT overwrites xpad(x) region)
    transpose_v_k<<<dim3(8, 4, 49), 256, 0, stream>>>((ushort*)(ws + OFF_VB), (ushort*)(ws + OFF_XT1));
    // 7) S = (q/sqrt(C)) . k^T  per spatial position
    gemm_bt<0, 2><<<dim3(2, 2, 49), 256, 0, stream>>>(
        (ushort*)(ws + OFF_QB), (ushort*)(ws + OFF_W1T),
        (float*)(ws + OFF_S), nullptr, nullptr, nullptr, 256, 256, 512, 512, 1);
    // 8) softmax over j
    softmax_k<<<3136, 256, 0, stream>>>((float*)(ws + OFF_S), (ushort*)(ws + OFF_ATT));
    // 9) virt = att @ V
    gemm_bt<0, 3><<<dim3(4, 2, 49), 256, 0, stream>>>(
        (ushort*)(ws + OFF_ATT), (ushort*)(ws + OFF_XT1),
        (float*)(ws + OFF_VIRT), nullptr, nullptr, nullptr, 256, 512, 256, 256, 1);
    // 10) layernorm + relu -> padded bf16
    ln_k<<<256, 256, 0, stream>>>((float*)(ws + OFF_VIRT), gamma, beta, (ushort*)(ws + OFF_VPAD));
    // 11) out = x + conv(virt, w_out)
    gemm_bt<1, 4><<<dim3(4, 98, 1), 256, 0, stream>>>(
        (ushort*)(ws + OFF_VPAD), (ushort*)(ws + OFF_WOT),
        out, nullptr, nullptr, (const float*)(ws + OFF_XF),
        12544, 512, 4608, 512, 9);
}